// Round 17
// baseline (1720.719 us; speedup 1.0000x reference)
//
#include <hip/hip_runtime.h>

#define N_NODES 8192
#define DEGREE 32
#define N_EDGES (N_NODES * DEGREE)
#define D_FEAT 256
#define SLICE_F 32                    // features per slice
#define N_SLICES 8                    // bf16 slice = 0.5 MB; slice = XCD affinity
#define RPW 16                        // rows per wave
#define WPB 4                         // waves per block
#define RPB (RPW * WPB)               // 64 rows per block
#define NBS (N_NODES / RPB)           // 128 blocks per slice
#define NB (N_SLICES * NBS)           // 1024 blocks (= 256 CU x 4 co-resident)
#define NITER 32

typedef unsigned int u32;
typedef unsigned short u16;

__device__ __forceinline__ float bflo(u32 v) {
  union { u32 i; float f; } c; c.i = v << 16; return c.f;
}
__device__ __forceinline__ float bfhi(u32 v) {
  union { u32 i; float f; } c; c.i = v & 0xffff0000u; return c.f;
}
__device__ __forceinline__ u32 pack2bf(float a, float b) {
  union { float f; u32 i; } ca, cb;
  ca.f = a; cb.f = b;
  u32 ra = (ca.i + 0x7FFFu + ((ca.i >> 16) & 1u)) >> 16;
  u32 rb = (cb.i + 0x7FFFu + ((cb.i >> 16) & 1u)) & 0xffff0000u;
  return ra | rb;
}

// ---------------------------------------------------------------------------
// Prep: row-normalize once; pack each edge as uint2 { dst*64 (byte offset of
// the bf16 slice row), w as f32 bits }. Block 0 also zeroes the barrier
// counters (d_ws is re-poisoned to 0xAA before every launch).
// ---------------------------------------------------------------------------
__global__ __launch_bounds__(256) void prep_kernel(
    const int* __restrict__ dst, const float* __restrict__ e,
    uint2* __restrict__ packed, u32* __restrict__ ctrs) {
  int g = blockIdx.x * 256 + threadIdx.x;
  float v = e[g];
  float s = v;
  for (int m = 1; m < 32; m <<= 1) s += __shfl_xor(s, m, 32);  // rows 32-aligned
  packed[g] = make_uint2((u32)dst[g] << 6, __float_as_uint(v / s));
  if (blockIdx.x == 0) {
    for (int i = threadIdx.x; i < 4096; i += 256) ctrs[i] = 0;
  }
}

// ---------------------------------------------------------------------------
// Persistent diffusion: one launch runs all 32 iterations.
// - Edge records staged in LDS ONCE (wave-local [16][33], conflict-free).
// - 16 B/lane gathers (round-13 shape): 1 KB per wave instruction.
// - Taps accumulate in REGISTERS; out written once at the end.
// - Per-slice barrier (128 blocks) between iterations: RELEASE atomicAdd
//   arrival (agent scope -> L2 writeback), RELAXED agent-scope spin
//   (no per-poll invalidate), one ACQUIRE load after (L1/L2 invalidate).
//   Slices never share mutable data, so slice-scope sync is sufficient.
// Deadlock safety: 1024 blocks, 17 KB LDS, VGPR capped by launch_bounds
// (256,4) -> 4 blocks/CU schedulable, 256 CUs -> all blocks co-resident.
// ---------------------------------------------------------------------------
__global__ __launch_bounds__(256, 4) void diffuse_persist(
    const uint2* __restrict__ packed, const float* __restrict__ hx,
    u16* __restrict__ bufA, u16* __restrict__ bufB,
    float* __restrict__ out, u32* __restrict__ ctrs) {
  __shared__ uint2 s_rec[WPB][RPW][33];   // 16.9 KB

  const int tid   = threadIdx.x;
  const int b     = blockIdx.x;
  const int slice = b & 7;            // XCD affinity heuristic (perf only)
  const int wb    = b >> 3;           // [0, 128)
  const int wave  = tid >> 6;
  const int lane  = tid & 63;
  const int r     = lane >> 2;        // row within wave 0..15
  const int fg    = lane & 3;         // 16 B feature group 0..3
  const int row_base = wb * RPB + wave * RPW;
  const int row_g    = row_base + r;

  // ---- stage this block's 512 edge records once (wave-local, no barrier) ----
  {
    const uint2* gsrc = packed + row_base * DEGREE;
#pragma unroll
    for (int t = 0; t < 8; ++t) {
      int idx = lane + 64 * t;
      s_rec[wave][idx >> 5][idx & 31] = gsrc[idx];
    }
  }

  const size_t sbytes = (size_t)N_NODES * SLICE_F * 2;   // 0.5 MB per slice
  const char* gH = (const char*)hx + slice * (SLICE_F * 4) + fg * 32;
  const char* gA = (const char*)bufA + slice * sbytes + fg * 16;
  const char* gB = (const char*)bufB + slice * sbytes + fg * 16;
  char* sA = (char*)bufA + slice * sbytes + (size_t)row_g * 64 + fg * 16;
  char* sB = (char*)bufB + slice * sbytes + (size_t)row_g * 64 + fg * 16;

  float t0=0.f,t1=0.f,t2=0.f,t3=0.f,t4=0.f,t5=0.f,t6=0.f,t7=0.f;  // tap regs

  for (int k = 1; k <= NITER; ++k) {
    float a0=0.f,a1=0.f,a2=0.f,a3=0.f,a4=0.f,a5=0.f,a6=0.f,a7=0.f;

    if (k == 1) {
      // gather f32 row-major h; byte offset = dst*1024 = rec.x << 4
#pragma unroll 4
      for (int j = 0; j < DEGREE; ++j) {
        uint2 rec = s_rec[wave][r][j];
        float w = __uint_as_float(rec.y);
        const char* p = gH + ((size_t)rec.x << 4);
        float4 v0 = *(const float4*)p;
        float4 v1 = *(const float4*)(p + 16);
        a0 += w*v0.x; a1 += w*v0.y; a2 += w*v0.z; a3 += w*v0.w;
        a4 += w*v1.x; a5 += w*v1.y; a6 += w*v1.z; a7 += w*v1.w;
      }
    } else {
      // k even reads bufA, k odd (>=3) reads bufB
      const char* xc = (k & 1) ? gB : gA;
#pragma unroll 8
      for (int j = 0; j < DEGREE; ++j) {
        uint2 rec = s_rec[wave][r][j];
        float w = __uint_as_float(rec.y);
        uint4 v = *(const uint4*)(xc + rec.x);     // 16 B/lane, 1 KB/instr
        a0 += w * bflo(v.x); a1 += w * bfhi(v.x);
        a2 += w * bflo(v.y); a3 += w * bfhi(v.y);
        a4 += w * bflo(v.z); a5 += w * bfhi(v.z);
        a6 += w * bflo(v.w); a7 += w * bfhi(v.w);
      }
    }

    // tap accumulate in registers (pre-rounding f32 acc)
    float coef = 0.f;
    if (k <= 2)       coef = 1.f;
    else if (k == 4)  coef = 1.f / 2.f;
    else if (k == 8)  coef = 1.f / 6.f;
    else if (k == 16) coef = 1.f / 24.f;
    else if (k == 32) coef = 1.f / 120.f;
    if (coef != 0.f) {
      t0 += coef*a0; t1 += coef*a1; t2 += coef*a2; t3 += coef*a3;
      t4 += coef*a4; t5 += coef*a5; t6 += coef*a6; t7 += coef*a7;
    }

    // store y (bf16, 16 B/lane, 1 KB contiguous per wave); k odd writes bufA
    char* yr = (k & 1) ? sA : sB;
    *(uint4*)yr = make_uint4(pack2bf(a0, a1), pack2bf(a2, a3),
                             pack2bf(a4, a5), pack2bf(a6, a7));

    // ---- per-slice barrier (not needed after the last iteration) ----
    if (k < NITER) {
      __syncthreads();   // drains each wave's stores (vmcnt 0 before barrier)
      if (tid == 0) {
        u32* c = ctrs + (((k - 1) * N_SLICES) + slice) * 16;  // 64 B stride
        __hip_atomic_fetch_add(c, 1u, __ATOMIC_RELEASE,
                               __HIP_MEMORY_SCOPE_AGENT);     // L2 writeback
        while (__hip_atomic_load(c, __ATOMIC_RELAXED,
                                 __HIP_MEMORY_SCOPE_AGENT) < (u32)NBS)
          __builtin_amdgcn_s_sleep(2);
        (void)__hip_atomic_load(c, __ATOMIC_ACQUIRE,
                                __HIP_MEMORY_SCOPE_AGENT);    // L1/L2 inv
      }
      __syncthreads();
    }
  }

  // ---- epilogue: write tap accumulators (only out write in the kernel) ----
  float* o = out + (size_t)row_g * D_FEAT + slice * SLICE_F + fg * 8;
  *(float4*)o       = make_float4(t0, t1, t2, t3);
  *(float4*)(o + 4) = make_float4(t4, t5, t6, t7);
}

extern "C" void kernel_launch(void* const* d_in, const int* in_sizes, int n_in,
                              void* d_out, int out_size, void* d_ws, size_t ws_size,
                              hipStream_t stream) {
  // inputs: src (unused — structure known), dst (int32), e (f32), h (f32)
  const int*   dst = (const int*)d_in[1];
  const float* e   = (const float*)d_in[2];
  const float* h   = (const float*)d_in[3];
  float* out = (float*)d_out;

  char* ws = (char*)d_ws;
  u16*   bufA   = (u16*)ws;                           // 4 MB sliced bf16
  u16*   bufB   = (u16*)(ws + (size_t)(4u << 20));    // 4 MB sliced bf16
  uint2* packed = (uint2*)(ws + (size_t)(8u << 20));  // 2 MB packed edges
  u32*   ctrs   = (u32*)(ws + (size_t)(10u << 20));   // 16 KB barrier counters

  prep_kernel<<<N_EDGES / 256, 256, 0, stream>>>(dst, e, packed, ctrs);
  diffuse_persist<<<NB, 256, 0, stream>>>(packed, h, bufA, bufB, out, ctrs);
}